// Round 7
// baseline (267.138 us; speedup 1.0000x reference)
//
#include <hip/hip_runtime.h>
#include <math.h>

// VectorQuantizer — bit-exact emulation of the numpy fp32 reference (proven R2-R6):
//   d[n,k] = fl32( fl32(x2[n]+c2[k]) - fl32(2 * fl32(exact_fp64_dot)) ), first argmin.
// R6 was SMEM-latency-bound (VALUBusy 30%): each k-iter waits on a 256B codebook
// s_load chain. R7 transposes the mapping: thread tid OWNS code k=tid and keeps
// cb[k][0..63] in 64 VGPRs; the block stages its 64 x-rows in LDS. Hot loop =
// uniform ds_read_b128 + v_fmac only (no global/scalar mem). Selection runs on
// ek = c2[k]-2*dot (x2 shift is argmin-invariant); near-best candidates are
// re-resolved with the bit-identical R2 fp64 formula and combined per row via a
// packed (dk,k) u64 atomicMin => exact reference first-argmin.

#define N_CODES   512
#define CODE_DIM  64
#define CH_STRIDE 4096                      // floats between channels
#define B_STRIDE  (CODE_DIM * CH_STRIDE)    // floats between batches
#define N_GW      1024                      // (b,h) row-groups
#define PAD       68                        // xs row pitch (16B-aligned, bank-spread)
#define CAP       8                         // candidate list per thread
#define THR       1.2e-4f                   // >= 2*(ref rounding + fast-dot error)

// numpy pairwise_sum for n=64 (loops.c.src) — setup kernel only.
__device__ __forceinline__ float np_pairwise_sum64(const float* a) {
    float r[8];
#pragma unroll
    for (int j = 0; j < 8; ++j) r[j] = a[j];
#pragma unroll
    for (int i = 8; i < 64; i += 8) {
#pragma unroll
        for (int j = 0; j < 8; ++j) r[j] = __fadd_rn(r[j], a[i + j]);
    }
    return __fadd_rn(__fadd_rn(__fadd_rn(r[0], r[1]), __fadd_rn(r[2], r[3])),
                     __fadd_rn(__fadd_rn(r[4], r[5]), __fadd_rn(r[6], r[7])));
}

__global__ void vq_setup_kernel(const float* __restrict__ cb, float* __restrict__ c2) {
    const int k = blockIdx.x * blockDim.x + threadIdx.x;
    if (k < N_CODES) {
        const float* row = cb + k * CODE_DIM;
        float sq[CODE_DIM];
#pragma unroll
        for (int j = 0; j < CODE_DIM; ++j) sq[j] = __fmul_rn(row[j], row[j]);
        c2[k] = np_pairwise_sum64(sq);
    }
}

__global__ __launch_bounds__(512, 2)
void vq_main_kernel(const float* __restrict__ in,
                    const float* __restrict__ cb,
                    const float* __restrict__ c2g,
                    float* __restrict__ out) {
    __shared__ __align__(16) float xs[64][PAD];          // 64 x-rows, 17.4 KB
    __shared__ unsigned long long s_list[CAP][512];      // packed (ek,n), 32 KB
    __shared__ float s_wmin[8][64];                      // per-wave per-row min ek
    __shared__ float s_bmin[64];                         // block-min ek per row
    __shared__ float s_x2e[64];                          // numpy-exact x2 per row
    __shared__ unsigned long long s_res[64];             // packed (dk_exact, k)

    const int tid  = threadIdx.x;       // == owned code k (0..511)
    const int lane = tid & 63;
    const int wid  = tid >> 6;          // 0..7
    const int gw   = blockIdx.x;        // (b,h) group

    // --- Stage x-rows into LDS (coalesced: consecutive tid -> consecutive w) --
    const float* src = in + (size_t)(gw >> 6) * B_STRIDE + (size_t)(gw & 63) * 64;
#pragma unroll
    for (int i = 0; i < 8; ++i) {
        const int idx = (i << 9) | tid;        // 0..4095 = c*64 + w
        const int c = idx >> 6, w = idx & 63;
        xs[w][c] = src[(size_t)c * CH_STRIDE + w];
    }

    // --- Own codebook row -> 64 VGPRs (16 x float4; lines fully reused in L1) --
    float cbv[CODE_DIM];
    {
        const float4* cb4 = (const float4*)(cb + (size_t)tid * CODE_DIM);
#pragma unroll
        for (int jj = 0; jj < 16; ++jj) {
            const float4 v = cb4[jj];
            cbv[4 * jj + 0] = v.x; cbv[4 * jj + 1] = v.y;
            cbv[4 * jj + 2] = v.z; cbv[4 * jj + 3] = v.w;
        }
    }
    const float c2v = c2g[tid];

    __syncthreads();

    // --- numpy-exact x2 per row (rolling 8-acc pairwise; R5-verified order) ---
    if (tid < 64) {
        float r[8];
#pragma unroll
        for (int j = 0; j < 8; ++j) r[j] = __fmul_rn(xs[tid][j], xs[tid][j]);
#pragma unroll
        for (int i = 8; i < 64; i += 8) {
#pragma unroll
            for (int j = 0; j < 8; ++j)
                r[j] = __fadd_rn(r[j], __fmul_rn(xs[tid][i + j], xs[tid][i + j]));
        }
        s_x2e[tid] = __fadd_rn(
            __fadd_rn(__fadd_rn(r[0], r[1]), __fadd_rn(r[2], r[3])),
            __fadd_rn(__fadd_rn(r[4], r[5]), __fadd_rn(r[6], r[7])));
        s_res[tid] = ~0ull;
    }

    // --- Hot loop: 64 rows x (16 uniform ds_read_b128 + 64 fmac + reduce) -----
    int cnt = 0;
    bool ovf = false;
#pragma unroll 1
    for (int n = 0; n < 64; ++n) {
        const float4* xr = (const float4*)xs[n];
        float a0 = 0.f, a1 = 0.f, a2 = 0.f, a3 = 0.f;
#pragma unroll
        for (int jj = 0; jj < 16; ++jj) {
            const float4 v = xr[jj];
            a0 = fmaf(v.x, cbv[4 * jj + 0], a0);
            a1 = fmaf(v.y, cbv[4 * jj + 1], a1);
            a2 = fmaf(v.z, cbv[4 * jj + 2], a2);
            a3 = fmaf(v.w, cbv[4 * jj + 3], a3);
        }
        const float dot = __fadd_rn(__fadd_rn(a0, a1), __fadd_rn(a2, a3));
        const float ek  = __fmaf_rn(-2.0f, dot, c2v);   // x2 dropped: argmin-invariant

        // wave-min over the 64 lanes (this wave's 64 codes)
        float m = ek;
#pragma unroll
        for (int s = 1; s < 64; s <<= 1) m = fminf(m, __shfl_xor(m, s, 64));

        if (ek <= m + THR) {                 // superset of block-near-best
            if (cnt < CAP) {
                s_list[cnt][tid] =
                    ((unsigned long long)__float_as_uint(ek) << 32) | (unsigned)n;
                ++cnt;
            } else {
                ovf = true;                  // safe fallback below
            }
        }
        if (lane == 0) s_wmin[wid][n] = m;
    }
    __syncthreads();

    // --- Block-min per row ----------------------------------------------------
    if (tid < 64) {
        float bm = s_wmin[0][tid];
#pragma unroll
        for (int w = 1; w < 8; ++w) bm = fminf(bm, s_wmin[w][tid]);
        s_bmin[tid] = bm;
    }
    __syncthreads();

    // --- Exact resolution (bit-identical R2 arithmetic) -----------------------
    // fp64 4-chain dot (cbv VGPRs x xs LDS), round once, numpy fp32 formula.
    auto resolve = [&](int n) {
        double b0 = 0.0, b1 = 0.0, b2 = 0.0, b3 = 0.0;
#pragma unroll
        for (int j = 0; j < CODE_DIM; j += 4) {
            b0 = fma((double)cbv[j + 0], (double)xs[n][j + 0], b0);
            b1 = fma((double)cbv[j + 1], (double)xs[n][j + 1], b1);
            b2 = fma((double)cbv[j + 2], (double)xs[n][j + 2], b2);
            b3 = fma((double)cbv[j + 3], (double)xs[n][j + 3], b3);
        }
        const double dot64 = (b0 + b1) + (b2 + b3);
        const float  ein   = (float)dot64;
        const float  tmp   = __fadd_rn(s_x2e[n], c2v);
        const float  dk    = __fsub_rn(tmp, __fmul_rn(2.0f, ein));
        atomicMin(&s_res[n],
                  ((unsigned long long)__float_as_uint(dk) << 32) | (unsigned)tid);
    };

    if (!ovf) {
#pragma unroll 1
        for (int i = 0; i < cnt; ++i) {
            const unsigned long long e = s_list[i][tid];
            const float ek = __uint_as_float((unsigned)(e >> 32));
            const int   n  = (int)(e & 0xFFFFFFFFull);
            if (ek <= s_bmin[n] + THR) resolve(n);
        }
    } else {                                  // ~never: full per-lane rescan
#pragma unroll 1
        for (int n = 0; n < 64; ++n) {
            const float4* xr = (const float4*)xs[n];
            float a0 = 0.f, a1 = 0.f, a2 = 0.f, a3 = 0.f;
#pragma unroll
            for (int jj = 0; jj < 16; ++jj) {
                const float4 v = xr[jj];
                a0 = fmaf(v.x, cbv[4 * jj + 0], a0);
                a1 = fmaf(v.y, cbv[4 * jj + 1], a1);
                a2 = fmaf(v.z, cbv[4 * jj + 2], a2);
                a3 = fmaf(v.w, cbv[4 * jj + 3], a3);
            }
            const float dot = __fadd_rn(__fadd_rn(a0, a1), __fadd_rn(a2, a3));
            const float ek  = __fmaf_rn(-2.0f, dot, c2v);
            if (ek <= s_bmin[n] + THR) resolve(n);
        }
    }
    __syncthreads();

    // --- Output: wave wid writes rows [wid*8, wid*8+8), coalesced 256B --------
    const size_t n0 = (size_t)gw * 64;
#pragma unroll 1
    for (int r = 0; r < 8; ++r) {
        const int row = (wid << 3) | r;
        const int bi  = (int)(s_res[row] & 0xFFFFFFFFull);   // uniform broadcast
        out[(n0 + row) * CODE_DIM + lane] = cb[(size_t)bi * CODE_DIM + lane];
    }
}

extern "C" void kernel_launch(void* const* d_in, const int* in_sizes, int n_in,
                              void* d_out, int out_size, void* d_ws, size_t ws_size,
                              hipStream_t stream) {
    const float* in  = (const float*)d_in[0];   // (16,64,64,64) fp32
    const float* cb  = (const float*)d_in[1];   // (512,64) fp32
    float*       out = (float*)d_out;           // (16,64,64,64) fp32
    float*       c2  = (float*)d_ws;            // 512 floats scratch

    vq_setup_kernel<<<dim3(2), dim3(256), 0, stream>>>(cb, c2);
    vq_main_kernel<<<dim3(N_GW), dim3(512), 0, stream>>>(in, cb, c2, out);
}